// Round 7
// baseline (164.678 us; speedup 1.0000x reference)
//
#include <hip/hip_runtime.h>

// Reference collapses: softmax row-sums are exactly 1, and einsum 'bqk,bvd->bqd'
// contracts k and v independently, so out[b,q,d] = sum_n v[b,n,d] (q-independent).
//   colsum[b,ch] = sum_n GN(x)[b,n,ch]
//   S[b,d]       = dot(Wv[d,:], colsum[b,:]) + 1024*bv[d]
//   out[b,d,:]   = dot(Wo[d,:], S[b,:]) + bo[d]  broadcast over hw
// Wq/bq/Wk/bk are provably dead (softmax row-sum == 1).
//
// Round 7. Rounds 5->6 proved the kernel is NOT latency-bound: doubling
// occupancy (34->67%) left dur unchanged at ~50us with HBM stuck at 2.2 TB/s.
// Diagnosis: phase 1's (b,g) partition reads 128-B chunks at 4-KB stride
// (group g = 32 contiguous n's of each of 1024 channel rows) — short-burst
// DRAM pattern at ~1/3 of streaming BW. Fix: repartition phase 1 by CHANNEL
// SLAB: block (b, slab) reads channels slab*32..slab*32+31 = 128 KB fully
// contiguous. Per-(ch,g) partials pg/q1/q2 go to LDS; group stats finish via
// 64 atomicAdds/block into gs1/gs2[b][g]; after a per-batch barrier each block
// writes colsum for its own 32 channels with ONE coherent store (no colsum
// atomics). colsum[b,ch] = K + sum_g inv_g*pg[ch][g],
//            K = sum(beta) - sum_g inv_g*mean_g*sumgamma_g.
// Fence-free relaxed agent-scope handshake (proven rounds 4-6), 3 per-batch
// barriers now. Phases 2/3 unchanged from round 6.

#define BATCH 16
#define CH    1024
#define NHW   1024
#define G     32
#define NPG   32
#define EPG   (NPG*CH)
#define EPSV  1e-5f
#define GRID  (BATCH*G)   // 512 blocks = 2/CU, co-resident (rounds 2/4/5/6 empirical)
#define TPB   1024

__device__ __forceinline__ float coh_load_f32(const float* p) {
    unsigned u = __hip_atomic_load((const unsigned*)p, __ATOMIC_RELAXED, __HIP_MEMORY_SCOPE_AGENT);
    return __uint_as_float(u);
}
__device__ __forceinline__ void coh_store_f32(float* p, float v) {
    __hip_atomic_store((unsigned*)p, __float_as_uint(v), __ATOMIC_RELAXED, __HIP_MEMORY_SCOPE_AGENT);
}
// coherent 8-byte load (2 floats), bypassing potentially-stale L1/L2
__device__ __forceinline__ void coh_load_f32x2(const float* p, float* d0, float* d1) {
    unsigned long long u = __hip_atomic_load((const unsigned long long*)p,
                                             __ATOMIC_RELAXED, __HIP_MEMORY_SCOPE_AGENT);
    *d0 = __uint_as_float((unsigned)(u & 0xffffffffu));
    *d1 = __uint_as_float((unsigned)(u >> 32));
}

// Fence-free per-batch barrier: relaxed arrive + relaxed poll by thread 0.
// __syncthreads() drains vmcnt(0) before s_barrier, so every thread's
// coherent/atomic writes are at the coherence point before the arrive.
__device__ __forceinline__ void batch_barrier(int* ctr, int expected)
{
    __syncthreads();
    if (threadIdx.x == 0) {
        __hip_atomic_fetch_add(ctr, 1, __ATOMIC_RELAXED, __HIP_MEMORY_SCOPE_AGENT);
        while (__hip_atomic_load(ctr, __ATOMIC_RELAXED, __HIP_MEMORY_SCOPE_AGENT) < expected)
            __builtin_amdgcn_s_sleep(1);
    }
    __syncthreads();
}

__global__ __launch_bounds__(TPB, 8) void fused_all(
    const float* __restrict__ x, const float* __restrict__ gamma,
    const float* __restrict__ beta,
    const float* __restrict__ Wv, const float* __restrict__ bv,
    const float* __restrict__ Wo, const float* __restrict__ bo,
    float* __restrict__ colsum, float* __restrict__ S,
    float* __restrict__ out,
    float* __restrict__ gs1, float* __restrict__ gs2,
    int* __restrict__ bar0, int* __restrict__ bar1, int* __restrict__ bar2)
{
    const int blk  = blockIdx.x;
    const int t    = threadIdx.x;
    const int lane = t & 63, wave = t >> 6;   // 16 waves
    const int b    = blk >> 5;                // batch, same meaning in all phases
    const int slab = blk & 31;                // channel slab (phase 1) / rowgroup (2,3)

    __shared__ float pg [32][33];             // gamma-weighted per-(ch,g) partials
    __shared__ float q1s[32][33];             // per-(ch,g) sum
    __shared__ float q2s[32][33];             // per-(ch,g) sum of squares
    __shared__ float sgam[32], invs[32], rb[16];
    __shared__ float Ksh;
    __shared__ float smem[CH];                // cs (phase 2) / sv (phase 3)

    // ---- phase 1a: contiguous load + per-(ch,g) partials ----
    // wave w owns channels chA = slab*32 + 2w, chA+1: two 4-KB rows, read as
    // 1-KiB fully-contiguous wave-loads (f4 index e = lane + i*64).
    // Group of f4 e is g = e>>3; the 8-lane cluster (lane>>3) at iteration i
    // covers exactly group i*8 + (lane>>3) of that channel.
    {
        const int chA = slab * 32 + wave * 2;
        const float4* rowA = reinterpret_cast<const float4*>(x + ((size_t)b * CH + chA) * NHW);
        const float4* rowB = rowA + (NHW / 4);
        const float4* gamma4 = reinterpret_cast<const float4*>(gamma);

        float4 a4[4], c4[4], g4[4];
        #pragma unroll
        for (int i = 0; i < 4; i++) a4[i] = rowA[lane + i * 64];
        #pragma unroll
        for (int i = 0; i < 4; i++) c4[i] = rowB[lane + i * 64];
        #pragma unroll
        for (int i = 0; i < 4; i++) g4[i] = gamma4[lane + i * 64];

        float bsum = beta[t];                 // 1024 threads cover beta exactly
        #pragma unroll
        for (int m = 1; m < 64; m <<= 1) bsum += __shfl_xor(bsum, m);
        if (lane == 0) rb[wave] = bsum;

        #pragma unroll
        for (int i = 0; i < 4; i++) {
            const int g = i * 8 + (lane >> 3);
            const float4 v = a4[i], u = c4[i], gm = g4[i];
            float pA = v.x * gm.x + v.y * gm.y + v.z * gm.z + v.w * gm.w;
            float sA = v.x + v.y + v.z + v.w;
            float qA = v.x * v.x + v.y * v.y + v.z * v.z + v.w * v.w;
            float pB = u.x * gm.x + u.y * gm.y + u.z * gm.z + u.w * gm.w;
            float sB = u.x + u.y + u.z + u.w;
            float qB = u.x * u.x + u.y * u.y + u.z * u.z + u.w * u.w;
            #pragma unroll
            for (int m = 1; m < 8; m <<= 1) {
                pA += __shfl_xor(pA, m); sA += __shfl_xor(sA, m); qA += __shfl_xor(qA, m);
                pB += __shfl_xor(pB, m); sB += __shfl_xor(sB, m); qB += __shfl_xor(qB, m);
            }
            if ((lane & 7) == 0) {
                const int cl = wave * 2;
                pg [cl][g] = pA; q1s[cl][g] = sA; q2s[cl][g] = qA;
                pg [cl + 1][g] = pB; q1s[cl + 1][g] = sB; q2s[cl + 1][g] = qB;
            }
        }
        // per-group sum of gamma (t<256: f4 e=t, group e>>3, 8-lane clusters)
        if (t < 256) {
            float4 gm = gamma4[t];
            float s = gm.x + gm.y + gm.z + gm.w;
            s += __shfl_xor(s, 1);
            s += __shfl_xor(s, 2);
            s += __shfl_xor(s, 4);
            if ((t & 7) == 0) sgam[t >> 3] = s;
        }
        __syncthreads();

        // ---- phase 1b: reduce q over this slab's 32 channels, tiny atomics ----
        // t = g*32 + ch; 32-lane shfl reduce over ch; 64 atomicAdds per block.
        {
            const int g  = t >> 5;
            const int ch = t & 31;
            float v1 = q1s[ch][g], v2 = q2s[ch][g];
            #pragma unroll
            for (int m = 1; m < 32; m <<= 1) { v1 += __shfl_xor(v1, m); v2 += __shfl_xor(v2, m); }
            if (ch == 0) {
                atomicAdd(&gs1[b * G + g], v1);
                atomicAdd(&gs2[b * G + g], v2);
            }
        }
    }
    batch_barrier(&bar0[b * 32], G);   // group stats complete for THIS batch

    // ---- phase 1c: inv/mean -> colsum for this slab's 32 channels ----
    {
        if (t < 32) {
            const float s1 = coh_load_f32(&gs1[b * G + t]);
            const float s2 = coh_load_f32(&gs2[b * G + t]);
            const float mean = s1 * (1.f / EPG);
            const float var  = s2 * (1.f / EPG) - mean * mean;
            const float inv  = rsqrtf(var + EPSV);
            invs[t] = inv;
            float term = inv * mean * sgam[t];
            #pragma unroll
            for (int m = 1; m < 32; m <<= 1) term += __shfl_xor(term, m);
            if (t == 0) {
                float bs = 0.f;
                #pragma unroll
                for (int w = 0; w < 16; w++) bs += rb[w];
                Ksh = bs - term;
            }
        }
        __syncthreads();
        // t = ch*32 + j: colsum[b, slab*32+ch] = K + sum_j inv[j]*pg[ch][j]
        const int ch = t >> 5, j = t & 31;
        float v = invs[j] * pg[ch][j];
        #pragma unroll
        for (int m = 1; m < 32; m <<= 1) v += __shfl_xor(v, m);
        if (j == 0)
            coh_store_f32(&colsum[b * CH + slab * 32 + ch], Ksh + v);  // single writer
    }
    batch_barrier(&bar1[b * 32], G);   // colsum[b,:] complete for THIS batch

    // ---- phase 2: S[b,d] = dot(Wv[d,:], colsum[b,:]) + 1024*bv[d] ----
    // rows d = slab*32..slab*32+31 (2 per wave); colsum[b,:] coherent -> LDS;
    // Wv rows normal cached loads (16x reuse across the batch-blocks).
    {
        if (t < 512) {
            float a0, a1;
            coh_load_f32x2(colsum + b * CH + t * 2, &a0, &a1);
            smem[t * 2 + 0] = a0; smem[t * 2 + 1] = a1;
        }
        __syncthreads();

        const int d0 = slab * 32 + wave * 2;
        const float4* cs4 = reinterpret_cast<const float4*>(smem);
        #pragma unroll
        for (int j = 0; j < 2; j++) {
            const int d = d0 + j;
            const float4* wrow = reinterpret_cast<const float4*>(Wv + (size_t)d * CH);
            float a = 0.f;
            #pragma unroll
            for (int i = 0; i < 4; i++) {
                int e4 = i * 64 + lane;
                float4 w = wrow[e4];
                float4 c = cs4[e4];
                a += w.x * c.x + w.y * c.y + w.z * c.z + w.w * c.w;
            }
            #pragma unroll
            for (int m = 1; m < 64; m <<= 1) a += __shfl_xor(a, m);
            if (lane == 0)
                coh_store_f32(&S[b * CH + d], a + (float)NHW * bv[d]);  // write-through
        }
    }
    batch_barrier(&bar2[b * 32], G);   // S[b,:] complete for THIS batch

    // ---- phase 3: out[b,d,:] = dot(Wo[d,:], S[b,:]) + bo[d], bcast over hw ----
    {
        if (t < 512) {
            float a0, a1;
            coh_load_f32x2(S + b * CH + t * 2, &a0, &a1);
            smem[t * 2 + 0] = a0; smem[t * 2 + 1] = a1;
        }
        __syncthreads();

        const int d0 = slab * 32 + wave * 2;
        const float4* s4 = reinterpret_cast<const float4*>(smem);
        #pragma unroll
        for (int j = 0; j < 2; j++) {
            const int d = d0 + j;
            const float4* wrow = reinterpret_cast<const float4*>(Wo + (size_t)d * CH);
            float a = 0.f;
            #pragma unroll
            for (int i = 0; i < 4; i++) {
                int e4 = i * 64 + lane;
                float4 w = wrow[e4];
                float4 c = s4[e4];
                a += w.x * c.x + w.y * c.y + w.z * c.z + w.w * c.w;
            }
            #pragma unroll
            for (int m = 1; m < 64; m <<= 1) a += __shfl_xor(a, m);  // all lanes hold sum
            const float val = a + bo[d];
            float4 v4 = make_float4(val, val, val, val);
            float4* op = reinterpret_cast<float4*>(out + ((size_t)b * CH + d) * NHW);
            #pragma unroll
            for (int i = 0; i < 4; i++) op[i * 64 + lane] = v4;  // 1 KiB contiguous per wave-store
        }
    }
}

extern "C" void kernel_launch(void* const* d_in, const int* in_sizes, int n_in,
                              void* d_out, int out_size, void* d_ws, size_t ws_size,
                              hipStream_t stream)
{
    const float* x     = (const float*)d_in[0];
    const float* gamma = (const float*)d_in[1];
    const float* beta  = (const float*)d_in[2];
    // d_in[3..6] = Wq, bq, Wk, bk: provably dead (softmax row-sum == 1)
    const float* Wv    = (const float*)d_in[7];
    const float* bv    = (const float*)d_in[8];
    const float* Wo    = (const float*)d_in[9];
    const float* bo    = (const float*)d_in[10];
    float* out = (float*)d_out;

    char* ws = (char*)d_ws;
    float* colsum = (float*)ws;                       // 64 KiB
    float* gs1    = (float*)(ws + 65536);             // 16*32 f = 2 KiB
    float* gs2    = (float*)(ws + 65536 + 2048);      // 2 KiB
    int*   bar0   = (int*)(ws + 65536 + 4096);        // 16 ctr x 128 B
    int*   bar1   = (int*)(ws + 65536 + 6144);
    int*   bar2   = (int*)(ws + 65536 + 8192);
    float* Sbuf   = (float*)(ws + 65536 + 10240);     // 64 KiB (not zeroed)

    // One memset zeroes colsum, gs1/gs2, and all barrier counters.
    hipMemsetAsync(ws, 0, 65536 + 10240, stream);
    fused_all<<<GRID, TPB, 0, stream>>>(x, gamma, beta, Wv, bv, Wo, bo,
                                        colsum, Sbuf, out, gs1, gs2,
                                        bar0, bar1, bar2);
}

// Round 8
// 157.976 us; speedup vs baseline: 1.0424x; 1.0424x over previous
//
#include <hip/hip_runtime.h>

// Reference collapses: softmax row-sums are exactly 1, and einsum 'bqk,bvd->bqd'
// contracts k and v independently, so out[b,q,d] = sum_n v[b,n,d] (q-independent).
//   colsum[b,ch] = sum_n GN(x)[b,n,ch]   (K1: block-local stats + atomics)
//   S[b,d]       = dot(Wv[d,:], colsum[b,:]) + 1024*bv[d]          (K2)
//   out[b,d,:]   = dot(Wo[d,:], S[b,:]) + bo[d]  broadcast over hw (K3)
// Wq/bq/Wk/bk are provably dead (softmax row-sum == 1).
//
// Round 8. R6 (2x TLP: no change) and R7 (contiguous reads: no change, +1
// barrier = +5us) falsified both the latency and DRAM-pattern theories. The
// invariant suspect is the software-barrier + coherent-op machinery (~7-10us
// per barrier). This round replaces software barriers with DISPATCH
// BOUNDARIES: 3 kernels, each phase individually timed by rocprof (definitive
// attribution), no spin loops, no relaxed-atomic coherent loads — plain
// cached loads everywhere (stream order + kernel-boundary cache semantics
// guarantee visibility). K1 = R6's verified phase 1; K2 = round-0's verified
// S matvec; K3 = R7's verified high-parallelism out phase (512 blocks,
// 16 waves — vs round-0 k4's 256 blocks x 4 waves).

#define BATCH 16
#define CH    1024
#define NHW   1024
#define G     32
#define NPG   32
#define EPG   (NPG*CH)
#define EPSV  1e-5f

// ---- K1: GN stats + colsum contribution; block (b,g) owns group (b,g) ----
__global__ __launch_bounds__(1024, 8) void k1_stats_colsum(
    const float* __restrict__ x, const float* __restrict__ gamma,
    const float* __restrict__ beta, float* __restrict__ colsum)
{
    const int blk  = blockIdx.x;
    const int t    = threadIdx.x;
    const int lane = t & 63, wave = t >> 6;   // 16 waves
    const int b    = blk >> 5, g = blk & 31;
    const int n4   = t & 7;                   // which float4 of the group's 32 n's
    const int c0   = t >> 3;                  // starting channel 0..127

    __shared__ float pch[CH];                 // gamma-weighted per-channel partials
    __shared__ float r1[16], r2[16], rb[16];

    const float4* xg = reinterpret_cast<const float4*>(x + (size_t)b * (CH * NHW) + g * NPG);
    const float4  gm = reinterpret_cast<const float4*>(gamma + g * NPG)[n4];

    float4 vb[8];
    #pragma unroll
    for (int k = 0; k < 8; k++)               // 8 independent loads in flight
        vb[k] = xg[(c0 + k * 128) * (NHW / 4) + n4];

    float s1 = 0.f, s2 = 0.f;
    #pragma unroll
    for (int k = 0; k < 8; k++) {
        const float4 v = vb[k];
        const int ch = c0 + k * 128;
        s1 += v.x + v.y + v.z + v.w;
        s2 += v.x * v.x + v.y * v.y + v.z * v.z + v.w * v.w;
        float p = v.x * gm.x + v.y * gm.y + v.z * gm.z + v.w * gm.w;
        p += __shfl_xor(p, 1);
        p += __shfl_xor(p, 2);
        p += __shfl_xor(p, 4);
        if (n4 == 0) pch[ch] = p;             // one writer per 8-lane cluster
    }
    float bsum = beta[t];                     // 1024 threads cover beta exactly
    #pragma unroll
    for (int m = 1; m < 64; m <<= 1) {
        s1 += __shfl_xor(s1, m); s2 += __shfl_xor(s2, m); bsum += __shfl_xor(bsum, m);
    }
    if (lane == 0) { r1[wave] = s1; r2[wave] = s2; rb[wave] = bsum; }
    __syncthreads();

    float S1 = 0.f, S2 = 0.f, SB = 0.f;
    #pragma unroll
    for (int w = 0; w < 16; w++) { S1 += r1[w]; S2 += r2[w]; SB += rb[w]; }
    const float mean = S1 * (1.f / EPG);
    const float var  = S2 * (1.f / EPG) - mean * mean;
    const float inv  = rsqrtf(var + EPSV);
    float sg = gm.x + gm.y + gm.z + gm.w;     // this group's 32 gammas
    sg += __shfl_xor(sg, 1);
    sg += __shfl_xor(sg, 2);
    sg += __shfl_xor(sg, 4);
    const float cshare = SB * (1.f / 32.f) - inv * mean * sg;

    atomicAdd(&colsum[b * CH + t], inv * pch[t] + cshare);  // one per thread
}

// ---- K2: S[b,d] = dot(Wv[d,:], colsum[b,:]) + 1024*bv[d]; one wave per d ----
__global__ __launch_bounds__(256) void k2_matvec_v(
    const float* __restrict__ Wv, const float* __restrict__ bv,
    const float* __restrict__ colsum, float* __restrict__ S)
{
    const int t = threadIdx.x;
    const int wave = t >> 6, lane = t & 63;
    const int d = blockIdx.x * 4 + wave;      // 256 blocks * 4 waves = 1024 rows
    const float4* wrow = reinterpret_cast<const float4*>(Wv + (size_t)d * CH);
    const float4* cs4  = reinterpret_cast<const float4*>(colsum);
    float acc[BATCH];
    #pragma unroll
    for (int b = 0; b < BATCH; b++) acc[b] = 0.f;
    #pragma unroll
    for (int i = 0; i < 4; i++) {
        int e4 = i * 64 + lane;
        float4 w = wrow[e4];
        #pragma unroll
        for (int b = 0; b < BATCH; b++) {
            float4 c = cs4[b * 256 + e4];
            acc[b] += w.x * c.x + w.y * c.y + w.z * c.z + w.w * c.w;
        }
    }
    #pragma unroll
    for (int b = 0; b < BATCH; b++) {
        float a = acc[b];
        #pragma unroll
        for (int m = 1; m < 64; m <<= 1) a += __shfl_xor(a, m);
        if (lane == 0) S[b * CH + d] = a + (float)NHW * bv[d];
    }
}

// ---- K3: out[b,d,:] = dot(Wo[d,:], S[b,:]) + bo[d], bcast over 1024 hw ----
// 512 blocks (b, slab) x 16 waves; wave computes 2 rows; S[b,:] staged in LDS.
__global__ __launch_bounds__(1024, 8) void k3_out(
    const float* __restrict__ Wo, const float* __restrict__ bo,
    const float* __restrict__ S, float* __restrict__ out)
{
    const int blk  = blockIdx.x;
    const int t    = threadIdx.x;
    const int lane = t & 63, wave = t >> 6;   // 16 waves
    const int b    = blk >> 5, slab = blk & 31;

    __shared__ float smem[CH];
    if (t < 256)
        reinterpret_cast<float4*>(smem)[t] =
            reinterpret_cast<const float4*>(S + (size_t)b * CH)[t];
    __syncthreads();

    const int d0 = slab * 32 + wave * 2;
    const float4* s4 = reinterpret_cast<const float4*>(smem);
    #pragma unroll
    for (int j = 0; j < 2; j++) {
        const int d = d0 + j;
        const float4* wrow = reinterpret_cast<const float4*>(Wo + (size_t)d * CH);
        float a = 0.f;
        #pragma unroll
        for (int i = 0; i < 4; i++) {
            int e4 = i * 64 + lane;
            float4 w = wrow[e4];
            float4 c = s4[e4];
            a += w.x * c.x + w.y * c.y + w.z * c.z + w.w * c.w;
        }
        #pragma unroll
        for (int m = 1; m < 64; m <<= 1) a += __shfl_xor(a, m);  // all lanes hold sum
        const float val = a + bo[d];
        float4 v4 = make_float4(val, val, val, val);
        float4* op = reinterpret_cast<float4*>(out + ((size_t)b * CH + d) * NHW);
        #pragma unroll
        for (int i = 0; i < 4; i++) op[i * 64 + lane] = v4;  // 1 KiB contiguous per wave-store
    }
}

extern "C" void kernel_launch(void* const* d_in, const int* in_sizes, int n_in,
                              void* d_out, int out_size, void* d_ws, size_t ws_size,
                              hipStream_t stream)
{
    const float* x     = (const float*)d_in[0];
    const float* gamma = (const float*)d_in[1];
    const float* beta  = (const float*)d_in[2];
    // d_in[3..6] = Wq, bq, Wk, bk: provably dead (softmax row-sum == 1)
    const float* Wv    = (const float*)d_in[7];
    const float* bv    = (const float*)d_in[8];
    const float* Wo    = (const float*)d_in[9];
    const float* bo    = (const float*)d_in[10];
    float* out = (float*)d_out;

    char* ws = (char*)d_ws;
    float* colsum = (float*)ws;                       // 16*1024 f = 64 KiB
    float* Sbuf   = (float*)(ws + 65536);             // 16*1024 f = 64 KiB

    hipMemsetAsync(colsum, 0, BATCH * CH * sizeof(float), stream);
    k1_stats_colsum<<<BATCH * G, 1024, 0, stream>>>(x, gamma, beta, colsum);
    k2_matvec_v    <<<256,       256, 0, stream>>>(Wv, bv, colsum, Sbuf);
    k3_out         <<<BATCH * G, 1024, 0, stream>>>(Wo, bo, Sbuf, out);
}